// Round 7
// baseline (214.094 us; speedup 1.0000x reference)
//
#include <hip/hip_runtime.h>
#include <hip/hip_bf16.h>

// GCN block: 3 x { t = relu(h @ W^T); h' = A_coo @ t (per sample) }
// B=8, N=10000, D=64, E=160000.
//
// Round 7:
//  - hipMemsetAsync(cnt) -> zero_kernel. rocprof showed the captured
//    fillBufferAligned costing 43-47us for a 40KB fill (~21% of total).
//  - spmm_csr_sliced: 4 feature-slices of 128 floats (256B). slice =
//    blockIdx&3; with XCD ~= blockIdx%8 round-robin, each XCD's gathers
//    touch only N*256B = 2.56MB < 4MB L2 -> near-all L2 hits (was ~60%
//    miss against the full 10.24MB bf16 table). 16-lane groups process 4
//    edges in parallel (dwordx4/lane), merged by __shfl_xor(16/32).
//  - gemm_relu_lds (LDS-staged, W in VGPRs, bf16 out) and CSR build
//    unchanged from round 6.

#define GCN_B 8
#define GCN_N 10000
#define GCN_D 64
#define GCN_E 160000
#define GCN_BN (GCN_B * GCN_N)

// ---------------- GEMM + ReLU (LDS-staged, bf16 out) ----------------
__global__ __launch_bounds__(256) void gemm_relu_lds(
    const float* __restrict__ h,
    const float* __restrict__ W,        // [64,64]; out[f] = sum_d h[d]*W[f*64+d]
    __hip_bfloat16* __restrict__ t,     // [N][B][64] bf16 flat
    int permute_in)
{
    __shared__ float hs[64 * 64];  // 16 KB

    const int tid = threadIdx.x;
    const int f = tid & 63;
    const int w = tid >> 6;
    const int g0 = blockIdx.x * 64;

    float4* hs4w = reinterpret_cast<float4*>(hs);
#pragma unroll
    for (int k = 0; k < 4; ++k) {
        int q = k * 256 + tid;
        int row = q >> 4;
        int c4 = q & 15;
        int g = g0 + row;
        const float4* src;
        if (permute_in) {
            int n = g >> 3, b = g & 7;
            src = reinterpret_cast<const float4*>(h + ((size_t)b * GCN_N + n) * 64) + c4;
        } else {
            src = reinterpret_cast<const float4*>(h + (size_t)g * 64) + c4;
        }
        hs4w[q] = *src;
    }

    float4 wr[16];
    const float4* W4 = reinterpret_cast<const float4*>(W);
#pragma unroll
    for (int i = 0; i < 16; ++i) wr[i] = W4[f * 16 + i];

    __syncthreads();

    const float4* hs4 = reinterpret_cast<const float4*>(hs);
#pragma unroll 4
    for (int rr = 0; rr < 16; ++rr) {
        const int row = w * 16 + rr;
        float acc = 0.f;
#pragma unroll
        for (int i = 0; i < 16; ++i) {
            float4 v = hs4[row * 16 + i];
            acc += v.x * wr[i].x + v.y * wr[i].y + v.z * wr[i].z + v.w * wr[i].w;
        }
        t[(size_t)(g0 + row) * 64 + f] = __float2bfloat16(fmaxf(acc, 0.0f));
    }
}

// ---------------- CSR build ----------------
__global__ __launch_bounds__(256) void zero_kernel(int* __restrict__ p, int n)
{
    int i = blockIdx.x * 256 + threadIdx.x;
    if (i < n) p[i] = 0;
}

__global__ __launch_bounds__(256) void hist_kernel(
    const int* __restrict__ rows, int* __restrict__ cnt, int E)
{
    int e = blockIdx.x * 256 + threadIdx.x;
    if (e < E) atomicAdd(&cnt[rows[e]], 1);
}

__global__ __launch_bounds__(256) void scan_kernel(
    const int* __restrict__ cnt, int* __restrict__ row_ptr, int* __restrict__ cur)
{
    __shared__ int sc[GCN_N];      // 40 KB
    __shared__ int part[256];
    const int tid = threadIdx.x;

    for (int i = tid; i < GCN_N; i += 256) sc[i] = cnt[i];
    __syncthreads();

    const int per = (GCN_N + 255) / 256;   // 40
    const int base = tid * per;
    int s = 0;
    for (int i = 0; i < per; ++i) {
        int idx = base + i;
        if (idx < GCN_N) s += sc[idx];
    }
    part[tid] = s;
    __syncthreads();
    for (int off = 1; off < 256; off <<= 1) {
        int add = (tid >= off) ? part[tid - off] : 0;
        __syncthreads();
        part[tid] += add;
        __syncthreads();
    }
    int run = part[tid] - s;
    for (int i = 0; i < per; ++i) {
        int idx = base + i;
        if (idx < GCN_N) {
            int c = sc[idx];
            sc[idx] = run;
            run += c;
        }
    }
    __syncthreads();
    for (int i = tid; i < GCN_N; i += 256) {
        int v = sc[i];
        row_ptr[i] = v;
        cur[i] = v;
    }
    if (tid == 0) row_ptr[GCN_N] = GCN_E;
}

__global__ __launch_bounds__(256) void scatter_kernel(
    const float* __restrict__ vals, const int* __restrict__ rows,
    const int* __restrict__ cols, int* __restrict__ cur,
    float* __restrict__ pval, int* __restrict__ pcol, int E)
{
    int e = blockIdx.x * 256 + threadIdx.x;
    if (e >= E) return;
    int pos = atomicAdd(&cur[rows[e]], 1);
    pval[pos] = vals[e];
    pcol[pos] = cols[e];
}

// ---------------- sliced CSR SpMM (bf16 gather, f32 accumulate) ----------------
// t: [N][64] uint4 (512 bf16/row). Slice s covers uint4 [s*16, s*16+16).
// Wave = (row r, slice s). 16-lane group g handles edges beg+g, beg+g+4, ...
// lane(i = lane&15) gathers uint4 chunk s*16+i of t[col]. Cross-group merge
// via shfl_xor(16/32); group 0 writes the 128-float output slice.
__global__ __launch_bounds__(256) void spmm_csr_sliced(
    const uint4* __restrict__ t4,
    const float* __restrict__ pval,
    const int* __restrict__ pcol,
    const int* __restrict__ row_ptr,
    float* __restrict__ out,
    int final_layout)                  // 0: out [n][512]; 1: out [b][n][64]
{
    const int bid = blockIdx.x;
    const int s = bid & 3;             // slice; XCD ~= bid%8 -> fixed slice/XCD
    const int rowgroup = bid >> 2;
    const int w = threadIdx.x >> 6;
    const int r = rowgroup * 4 + w;    // N = 10000 = 2500*4, exact
    const int lane = threadIdx.x & 63;
    const int g = lane >> 4;
    const int i = lane & 15;

    const int beg = row_ptr[r];
    const int end = row_ptr[r + 1];

    float a[8];
#pragma unroll
    for (int k = 0; k < 8; ++k) a[k] = 0.f;

    const int chunk = s * 16 + i;

    for (int j = beg + g; j < end; j += 4) {
        const float v = pval[j];
        const int c = pcol[j];
        uint4 u = t4[(size_t)c * 64 + chunk];
        a[0] += v * __uint_as_float(u.x << 16);
        a[1] += v * __uint_as_float(u.x & 0xffff0000u);
        a[2] += v * __uint_as_float(u.y << 16);
        a[3] += v * __uint_as_float(u.y & 0xffff0000u);
        a[4] += v * __uint_as_float(u.z << 16);
        a[5] += v * __uint_as_float(u.z & 0xffff0000u);
        a[6] += v * __uint_as_float(u.w << 16);
        a[7] += v * __uint_as_float(u.w & 0xffff0000u);
    }

#pragma unroll
    for (int k = 0; k < 8; ++k) {
        a[k] += __shfl_xor(a[k], 16, 64);
        a[k] += __shfl_xor(a[k], 32, 64);
    }

    if (g == 0) {
        float* op;
        if (!final_layout) {
            op = out + (size_t)r * 512 + s * 128 + i * 8;
        } else {
            const int q = s * 128 + i * 8;       // global feature index
            const int b = q >> 6;
            const int d = q & 63;
            op = out + ((size_t)b * GCN_N + r) * 64 + d;
        }
        *reinterpret_cast<float4*>(op)     = make_float4(a[0], a[1], a[2], a[3]);
        *reinterpret_cast<float4*>(op + 4) = make_float4(a[4], a[5], a[6], a[7]);
    }
}

extern "C" void kernel_launch(void* const* d_in, const int* in_sizes, int n_in,
                              void* d_out, int out_size, void* d_ws, size_t ws_size,
                              hipStream_t stream) {
    const float* x    = (const float*)d_in[0];
    const float* W0   = (const float*)d_in[1];
    const float* W1   = (const float*)d_in[2];
    const float* W2   = (const float*)d_in[3];
    const float* vals = (const float*)d_in[4];
    const int*   rows = (const int*)d_in[5];
    const int*   cols = (const int*)d_in[6];
    float* out = (float*)d_out;

    const size_t t_bytes = (size_t)GCN_BN * GCN_D * sizeof(__hip_bfloat16); // 10,240,000

    char* ws = (char*)d_ws;
    __hip_bfloat16* t = (__hip_bfloat16*)ws;
    size_t off = (t_bytes + 255) / 256 * 256;
    int*   row_ptr = (int*)(ws + off); off += ((GCN_N + 1) * 4 + 255) / 256 * 256;
    int*   cur     = (int*)(ws + off); off += (GCN_N * 4 + 255) / 256 * 256;
    int*   cnt     = (int*)(ws + off); off += (GCN_N * 4 + 255) / 256 * 256;
    float* pval    = (float*)(ws + off); off += GCN_E * 4;
    int*   pcol    = (int*)(ws + off); off += GCN_E * 4;

    const int gemm_grid = GCN_BN / 64;                // 1250 tiles
    const int edge_grid = (GCN_E + 255) / 256;        // 625
    const int spmm_grid = (GCN_N / 4) * 4;            // 2500 rowgroups x 4 slices

    // Build CSR once; reused by all 3 layers.
    zero_kernel<<<(GCN_N + 255) / 256, 256, 0, stream>>>(cnt, GCN_N);
    hist_kernel<<<edge_grid, 256, 0, stream>>>(rows, cnt, GCN_E);
    scan_kernel<<<1, 256, 0, stream>>>(cnt, row_ptr, cur);
    scatter_kernel<<<edge_grid, 256, 0, stream>>>(vals, rows, cols, cur, pval, pcol, GCN_E);

    const uint4* t4 = (const uint4*)t;

    // layer 1: x is [b][n][64] -> permuted read; intermediates in [n][512]
    gemm_relu_lds<<<gemm_grid, 256, 0, stream>>>(x, W0, t, 1);
    spmm_csr_sliced<<<spmm_grid, 256, 0, stream>>>(t4, pval, pcol, row_ptr, out, 0);

    // layer 2
    gemm_relu_lds<<<gemm_grid, 256, 0, stream>>>(out, W1, t, 0);
    spmm_csr_sliced<<<spmm_grid, 256, 0, stream>>>(t4, pval, pcol, row_ptr, out, 0);

    // layer 3: final output in [b][n][64]
    gemm_relu_lds<<<gemm_grid, 256, 0, stream>>>(out, W2, t, 0);
    spmm_csr_sliced<<<spmm_grid, 256, 0, stream>>>(t4, pval, pcol, row_ptr, out, 1);
}